// Round 2
// baseline (112.739 us; speedup 1.0000x reference)
//
#include <hip/hip_runtime.h>
#include <hip/hip_bf16.h>

// HalfKP input layer:
// out[b,c] = bias[c] + sum_f p[b,f] * (W[k0,f,c] + W[k1,f,c]) + W[k0,640,c] + W[k1,640,c]
// B=1024, K=64, F=640, C=256.  W is (64, 641, 256) fp32 = 42 MB.
//
// piece_positions arrives as int32 (one int per bool) per the harness's
// integer-input convention: (B, 640) int32, values 0/1.
//
// Block per sample, thread per channel. Each wave ballots 64 piece flags into
// a wave-uniform 64-bit mask, then walks set bits with scalar ctz -> uniform
// branches, coalesced 1 KB weight-row loads.

#define C_DIM 256
#define ROW_STRIDE 256          // floats per feature row
#define SLAB_STRIDE (641 * 256) // floats per king slab

__global__ __launch_bounds__(256)
void halfkp_kernel(const int* __restrict__ pieces,   // (B, 640) int32 0/1
                   const int* __restrict__ kings,    // (B, 2)
                   const float* __restrict__ W,      // (64, 641, 256)
                   const float* __restrict__ bias,   // (256,)
                   float* __restrict__ out)          // (B, 256)
{
    const int b = blockIdx.x;
    const int c = threadIdx.x;
    const int lane = c & 63;

    const int k0 = kings[2 * b + 0];
    const int k1 = kings[2 * b + 1];

    const float* W0 = W + (size_t)k0 * SLAB_STRIDE + c;
    const float* W1 = W + (size_t)k1 * SLAB_STRIDE + c;

    // bias + the two always-active "extra" rows (feature index 640)
    float acc = bias[c] + W0[640 * ROW_STRIDE] + W1[640 * ROW_STRIDE];

    const int* pi = pieces + (size_t)b * 640;

    #pragma unroll
    for (int ch = 0; ch < 10; ++ch) {
        // 64 coalesced int32 loads per wave -> one wave-uniform 64-bit mask.
        int v = pi[ch * 64 + lane];
        unsigned long long m = __ballot(v != 0);

        const float* b0 = W0 + ch * 64 * ROW_STRIDE;
        const float* b1 = W1 + ch * 64 * ROW_STRIDE;

        while (m) {
            const int f = __builtin_ctzll(m);   // s_ff1 on SGPR mask
            m &= m - 1;
            acc += b0[f * ROW_STRIDE] + b1[f * ROW_STRIDE];
        }
    }

    out[(size_t)b * C_DIM + c] = acc;
}

extern "C" void kernel_launch(void* const* d_in, const int* in_sizes, int n_in,
                              void* d_out, int out_size, void* d_ws, size_t ws_size,
                              hipStream_t stream) {
    const int* pieces = (const int*)d_in[0];   // (1024, 640) int32 bools
    const int* kings  = (const int*)d_in[1];   // (1024, 2) int32
    const float* W    = (const float*)d_in[2]; // (64, 641, 256) f32
    const float* bias = (const float*)d_in[3]; // (256,) f32
    float* out        = (float*)d_out;         // (1024, 256) f32

    const int B = in_sizes[1] / 2; // 1024
    halfkp_kernel<<<dim3(B), dim3(C_DIM), 0, stream>>>(pieces, kings, W, bias, out);
}

// Round 3
// 82.038 us; speedup vs baseline: 1.3742x; 1.3742x over previous
//
#include <hip/hip_runtime.h>
#include <hip/hip_bf16.h>

// HalfKP input layer:
// out[b,c] = bias[c] + sum_f p[b,f] * (W[k0,f,c] + W[k1,f,c]) + W[k0,640,c] + W[k1,640,c]
// B=1024, K=64, F=640, C=256.  W is (64, 641, 256) fp32 = 42 MB.
//
// R3: latency attack. Block = 1 sample, 512 threads (8 waves).
//  - Phase 0: ballot+rank builds the sorted active-feature index list in LDS
//    (deterministic, no atomics).
//  - Phase 1: thread owns 4 channels (float4); one wave covers a full 1 KB
//    weight row per dwordx4. Waves stride the list 8-way, unroll 4 entries
//    -> 8 independent 16B loads in flight.
//  - Phase 2: LDS reduction over the 8 wave partials.

#define F_DIM 640
#define C_DIM 256
#define SLAB_STRIDE (641 * 256) // floats per king slab

__global__ __launch_bounds__(512)
void halfkp_kernel(const int* __restrict__ pieces,   // (B, 640) int32 0/1
                   const int* __restrict__ kings,    // (B, 2)
                   const float* __restrict__ W,      // (64, 641, 256)
                   const float* __restrict__ bias,   // (256,)
                   float* __restrict__ out)          // (B, 256)
{
    __shared__ unsigned short s_idx[F_DIM];   // sorted active feature indices
    __shared__ int s_cnt[10];                 // per-64-feature-group popcounts
    __shared__ int s_base[11];                // exclusive prefix
    __shared__ float s_part[8][C_DIM];        // per-wave partials (8 KB)

    const int b = blockIdx.x;
    const int t = threadIdx.x;
    const int w = t >> 6;        // wave 0..7
    const int lane = t & 63;

    const int* pi = pieces + (size_t)b * F_DIM;

    // ---- Phase 0: build sorted active-feature list (deterministic) ----
    // groups 0..7: feature f = t (wave w covers group w)
    // groups 8..9: feature f = 512 + t for t < 128 (waves 0,1)
    const int v1 = pi[t];
    const unsigned long long m1 = __ballot(v1 != 0);
    const int v2 = (t < 128) ? pi[512 + t] : 0;
    const unsigned long long m2 = __ballot(v2 != 0);

    if (lane == 0) {
        s_cnt[w] = (int)__popcll(m1);
        if (w < 2) s_cnt[8 + w] = (int)__popcll(m2);
    }
    __syncthreads();
    if (t == 0) {
        int s = 0;
        #pragma unroll
        for (int g = 0; g < 10; ++g) { s_base[g] = s; s += s_cnt[g]; }
        s_base[10] = s;
    }
    __syncthreads();

    const unsigned long long ltmask = (1ull << lane) - 1ull;
    if (v1 != 0) {
        const int r = (int)__popcll(m1 & ltmask);
        s_idx[s_base[w] + r] = (unsigned short)t;
    }
    if (t < 128 && v2 != 0) {
        const int r = (int)__popcll(m2 & ltmask);
        s_idx[s_base[8 + w] + r] = (unsigned short)(512 + t);
    }
    __syncthreads();
    const int n = s_base[10];

    // ---- Phase 1: accumulate (thread = 4 channels via float4) ----
    const int k0 = kings[2 * b + 0];
    const int k1 = kings[2 * b + 1];
    const float4* __restrict__ W0 = (const float4*)(W + (size_t)k0 * SLAB_STRIDE);
    const float4* __restrict__ W1 = (const float4*)(W + (size_t)k1 * SLAB_STRIDE);
    // row f occupies float4 indices [f*64, f*64+64); lane l takes f*64 + l.

    float ax = 0.f, ay = 0.f, az = 0.f, aw = 0.f;
    if (w == 0) {
        // bias + the two always-active extra rows (feature 640), added once.
        float4 bb = ((const float4*)bias)[lane];
        float4 e0 = W0[640 * 64 + lane];
        float4 e1 = W1[640 * 64 + lane];
        ax = bb.x + e0.x + e1.x;
        ay = bb.y + e0.y + e1.y;
        az = bb.z + e0.z + e1.z;
        aw = bb.w + e0.w + e1.w;
    }

    int e = w;
    for (; e + 24 < n; e += 32) {
        const int fa = s_idx[e];
        const int fb = s_idx[e + 8];
        const int fc = s_idx[e + 16];
        const int fd = s_idx[e + 24];
        const float4 a0 = W0[fa * 64 + lane];
        const float4 a1 = W1[fa * 64 + lane];
        const float4 b0 = W0[fb * 64 + lane];
        const float4 b1 = W1[fb * 64 + lane];
        const float4 c0 = W0[fc * 64 + lane];
        const float4 c1 = W1[fc * 64 + lane];
        const float4 d0 = W0[fd * 64 + lane];
        const float4 d1 = W1[fd * 64 + lane];
        ax += (a0.x + a1.x) + (b0.x + b1.x) + (c0.x + c1.x) + (d0.x + d1.x);
        ay += (a0.y + a1.y) + (b0.y + b1.y) + (c0.y + c1.y) + (d0.y + d1.y);
        az += (a0.z + a1.z) + (b0.z + b1.z) + (c0.z + c1.z) + (d0.z + d1.z);
        aw += (a0.w + a1.w) + (b0.w + b1.w) + (c0.w + c1.w) + (d0.w + d1.w);
    }
    for (; e < n; e += 8) {
        const int f = s_idx[e];
        const float4 a0 = W0[f * 64 + lane];
        const float4 a1 = W1[f * 64 + lane];
        ax += a0.x + a1.x;
        ay += a0.y + a1.y;
        az += a0.z + a1.z;
        aw += a0.w + a1.w;
    }

    // ---- Phase 2: reduce the 8 wave partials ----
    float4* row = (float4*)&s_part[w][0];
    row[lane] = make_float4(ax, ay, az, aw);
    __syncthreads();

    if (t < C_DIM) {
        float s = 0.f;
        #pragma unroll
        for (int wv = 0; wv < 8; ++wv) s += s_part[wv][t];
        out[(size_t)b * C_DIM + t] = s;
    }
}

extern "C" void kernel_launch(void* const* d_in, const int* in_sizes, int n_in,
                              void* d_out, int out_size, void* d_ws, size_t ws_size,
                              hipStream_t stream) {
    const int* pieces = (const int*)d_in[0];   // (1024, 640) int32 bools
    const int* kings  = (const int*)d_in[1];   // (1024, 2) int32
    const float* W    = (const float*)d_in[2]; // (64, 641, 256) f32
    const float* bias = (const float*)d_in[3]; // (256,) f32
    float* out        = (float*)d_out;         // (1024, 256) f32

    const int B = in_sizes[1] / 2; // 1024
    halfkp_kernel<<<dim3(B), dim3(512), 0, stream>>>(pieces, kings, W, bias, out);
}

// Round 4
// 72.965 us; speedup vs baseline: 1.5451x; 1.1243x over previous
//
#include <hip/hip_runtime.h>
#include <hip/hip_bf16.h>

// HalfKP input layer, king-grouped formulation:
//   out[b,c] = bias[c] + sum over (persp s) of [ sum_f p[b,f]*W[k_s(b),f,c] + W[k_s(b),640,c] ]
// B=1024, K=64, F=640, C=256.  W is (64, 641, 256) fp32 = 42 MB.
//
// R4: group the 2048 (sample,persp) entries by king so each weight row is
// read once per block and reused across <=16 register accumulators.
//   A: build per-king entry lists (atomics; list order does not affect any
//      fp accumulation order -> deterministic output).
//   B: grid (64 kings, 4 chunks of 16 entries), 512 thr. LDS holds a 16-bit
//      per-feature activity mask (f=640 forced active -> "extra" rows free).
//      Wave w strides f by 8; row loaded as float4 (lane = 4 channels);
//      unrolled predicated adds into acc[16] (static VGPR indices,
//      wave-uniform scalar branches). 3-round LDS reduce over 8 waves,
//      store per-entry partials to ws.
//   C: out = bias + partial[0] + partial[1].

#define F_DIM 640
#define C_DIM 256
#define SLAB_STRIDE (641 * 256)   // floats per king slab
#define NKING 64
#define CH 16                     // entries per chunk
#define NCH 4                     // chunks per king
#define LCAP 256                  // list capacity per king (>> any plausible count)

// ws layout (bytes)
#define WS_CNT_OFF 0                        // 64 * 4
#define WS_LIST_OFF 1024                    // 64 * 256 * 4 = 64 KB
#define WS_PART_OFF 131072                  // 2 * 1024 * 256 * 4 = 2 MB
#define WS_NEED (WS_PART_OFF + 2 * 1024 * 256 * 4)

__global__ __launch_bounds__(256)
void build_lists(const int* __restrict__ kings, int* __restrict__ cnt,
                 int* __restrict__ list, int nent)
{
    const int id = blockIdx.x * 256 + threadIdx.x;   // entry id = b*2 + persp
    if (id >= nent) return;
    const int b = id >> 1, p = id & 1;
    const int k = kings[2 * b + p];
    const int pos = atomicAdd(&cnt[k], 1);
    if (pos < LCAP) list[k * LCAP + pos] = id;
}

__global__ __launch_bounds__(512)
void halfkp_group(const int* __restrict__ pieces,   // (B, 640) int32 0/1
                  const float* __restrict__ W,      // (64, 641, 256)
                  const int* __restrict__ cnt,
                  const int* __restrict__ list,
                  float* __restrict__ partial)      // (2, 1024, 256)
{
    const int k  = blockIdx.x;
    const int ci = blockIdx.y;
    const int t  = threadIdx.x;
    const int wv = t >> 6;
    const int lane = t & 63;

    __shared__ int s_ent[CH];
    __shared__ unsigned short s_mask[F_DIM + 1];
    __shared__ float4 s_red[4][CH][64];   // 64 KB

    const int n_k = min(cnt[k], LCAP);
    const float4* __restrict__ Wk = (const float4*)(W + (size_t)k * SLAB_STRIDE);

    for (int base0 = 0; base0 < n_k; base0 += NCH * CH) {
        const int base = base0 + ci * CH;
        const int nc = min(n_k - base, CH);
        if (nc <= 0) continue;                 // block-uniform

        if (t < CH) s_ent[t] = (t < nc) ? list[k * LCAP + base + t] : 0;
        __syncthreads();

        // Build 16-bit activity mask per feature row. Row 640 always active.
        for (int f = t; f <= F_DIM; f += 512) {
            unsigned m;
            if (f == F_DIM) {
                m = (1u << nc) - 1u;           // nc <= 16
            } else {
                m = 0;
                #pragma unroll
                for (int j = 0; j < CH; ++j) {
                    if (j < nc) {
                        const int b = s_ent[j] >> 1;
                        m |= (pieces[(size_t)b * F_DIM + f] != 0 ? 1u : 0u) << j;
                    }
                }
            }
            s_mask[f] = (unsigned short)m;
        }
        __syncthreads();

        float4 acc[CH];
        #pragma unroll
        for (int e = 0; e < CH; ++e) acc[e] = make_float4(0.f, 0.f, 0.f, 0.f);

        // Wave wv covers rows f ≡ wv (mod 8); one dwordx4 per row per wave
        // spans all 256 channels (lane = 4 channels).
        for (int f = wv; f <= F_DIM; f += 8) {
            const unsigned m = __builtin_amdgcn_readfirstlane((unsigned)s_mask[f]);
            const float4 w4 = Wk[f * 64 + lane];
            #pragma unroll
            for (int e = 0; e < CH; ++e) {
                if (m & (1u << e)) {
                    acc[e].x += w4.x; acc[e].y += w4.y;
                    acc[e].z += w4.z; acc[e].w += w4.w;
                }
            }
        }

        // 3-round deterministic reduce: 8 -> 4 -> 2 -> 1 waves.
        __syncthreads();
        if (wv >= 4) {
            #pragma unroll
            for (int e = 0; e < CH; ++e) s_red[wv - 4][e][lane] = acc[e];
        }
        __syncthreads();
        if (wv < 4) {
            #pragma unroll
            for (int e = 0; e < CH; ++e) {
                const float4 r = s_red[wv][e][lane];
                acc[e].x += r.x; acc[e].y += r.y; acc[e].z += r.z; acc[e].w += r.w;
            }
        }
        __syncthreads();
        if (wv == 2 || wv == 3) {
            #pragma unroll
            for (int e = 0; e < CH; ++e) s_red[wv - 2][e][lane] = acc[e];
        }
        __syncthreads();
        if (wv < 2) {
            #pragma unroll
            for (int e = 0; e < CH; ++e) {
                const float4 r = s_red[wv][e][lane];
                acc[e].x += r.x; acc[e].y += r.y; acc[e].z += r.z; acc[e].w += r.w;
            }
        }
        __syncthreads();
        if (wv == 1) {
            #pragma unroll
            for (int e = 0; e < CH; ++e) s_red[0][e][lane] = acc[e];
        }
        __syncthreads();
        if (wv == 0) {
            #pragma unroll
            for (int e = 0; e < CH; ++e) {
                const float4 r = s_red[0][e][lane];
                acc[e].x += r.x; acc[e].y += r.y; acc[e].z += r.z; acc[e].w += r.w;
            }
            for (int e = 0; e < CH; ++e) {
                if (e < nc) {
                    const int id = s_ent[e];
                    const int b = id >> 1, p = id & 1;
                    ((float4*)partial)[((size_t)p * 1024 + b) * 64 + lane] = acc[e];
                }
            }
        }
        __syncthreads();   // protect s_ent/s_mask/s_red before next sweep
    }
}

__global__ __launch_bounds__(256)
void finalize(const float* __restrict__ partial,
              const float* __restrict__ bias,
              float* __restrict__ out)
{
    const int i = blockIdx.x * 256 + threadIdx.x;    // float4 index, B*64 total
    const float4 b4 = ((const float4*)bias)[i & 63];
    const float4 p0 = ((const float4*)partial)[i];
    const float4 p1 = ((const float4*)partial)[1024 * 64 + i];
    float4 o;
    o.x = b4.x + p0.x + p1.x;
    o.y = b4.y + p0.y + p1.y;
    o.z = b4.z + p0.z + p1.z;
    o.w = b4.w + p0.w + p1.w;
    ((float4*)out)[i] = o;
}

// ---- fallback (R3 path) if ws is too small ----
__global__ __launch_bounds__(256)
void halfkp_fallback(const int* __restrict__ pieces, const int* __restrict__ kings,
                     const float* __restrict__ W, const float* __restrict__ bias,
                     float* __restrict__ out)
{
    const int b = blockIdx.x;
    const int c = threadIdx.x;
    const int lane = c & 63;
    const int k0 = kings[2 * b + 0];
    const int k1 = kings[2 * b + 1];
    const float* W0 = W + (size_t)k0 * SLAB_STRIDE + c;
    const float* W1 = W + (size_t)k1 * SLAB_STRIDE + c;
    float acc = bias[c] + W0[640 * 256] + W1[640 * 256];
    const int* pi = pieces + (size_t)b * F_DIM;
    #pragma unroll
    for (int ch = 0; ch < 10; ++ch) {
        int v = pi[ch * 64 + lane];
        unsigned long long m = __ballot(v != 0);
        const float* b0 = W0 + ch * 64 * 256;
        const float* b1 = W1 + ch * 64 * 256;
        while (m) {
            const int f = __builtin_ctzll(m);
            m &= m - 1;
            acc += b0[f * 256] + b1[f * 256];
        }
    }
    out[(size_t)b * C_DIM + c] = acc;
}

extern "C" void kernel_launch(void* const* d_in, const int* in_sizes, int n_in,
                              void* d_out, int out_size, void* d_ws, size_t ws_size,
                              hipStream_t stream) {
    const int* pieces = (const int*)d_in[0];   // (1024, 640) int32 bools
    const int* kings  = (const int*)d_in[1];   // (1024, 2) int32
    const float* W    = (const float*)d_in[2]; // (64, 641, 256) f32
    const float* bias = (const float*)d_in[3]; // (256,) f32
    float* out        = (float*)d_out;         // (1024, 256) f32

    const int B = in_sizes[1] / 2;             // 1024
    const int nent = 2 * B;

    if (ws_size < (size_t)WS_NEED) {
        halfkp_fallback<<<dim3(B), dim3(C_DIM), 0, stream>>>(pieces, kings, W, bias, out);
        return;
    }

    int* cnt      = (int*)((char*)d_ws + WS_CNT_OFF);
    int* list     = (int*)((char*)d_ws + WS_LIST_OFF);
    float* part   = (float*)((char*)d_ws + WS_PART_OFF);

    hipMemsetAsync(cnt, 0, NKING * sizeof(int), stream);
    build_lists<<<dim3((nent + 255) / 256), dim3(256), 0, stream>>>(kings, cnt, list, nent);
    halfkp_group<<<dim3(NKING, NCH), dim3(512), 0, stream>>>(pieces, W, cnt, list, part);
    finalize<<<dim3(B * 64 / 256), dim3(256), 0, stream>>>(part, bias, out);
}